// Round 6
// baseline (303.307 us; speedup 1.0000x reference)
//
#include <hip/hip_runtime.h>

// TNNCell scan: B=4096 chains, T=512 steps.
// Layout: 32 lanes/chain, 2 chains/wave -> 2048 waves = 2 waves/SIMD.
//   lanes [0..15]  : chain0 conduct columns (sigmoid, conducts 0..14)
//   lanes [16..31] : chain1 conduct columns
//   lanes [32..47] : chain0 tanh columns (h units 0..15)
//   lanes [48..63] : chain1 tanh columns
// One 11-FMA column per lane; 16-lane DPP tree per row; cross-half exchange
// via permlane32_swap made RETURN-ORDER-AGNOSTIC: other = v ^ sw[0] ^ sw[1]
// (the swap outputs at lane i always form the multiset {v[i], v[i^32]}).
// Update u_r = own + other where conduct-own = t_r, h-own = |p_r + b2r|
// (bias + abs applied via lane-constant add/and masks) -> identical on all
// lanes of the chain, so every lane updates all 4 states locally.

template <int CTRL>
__device__ __forceinline__ float dppadd(float v) {
  int x = __builtin_amdgcn_update_dpp(0, __float_as_int(v), CTRL, 0xF, 0xF, true);
  return v + __int_as_float(x);
}
#define DPP_XOR1 0xB1   // quad_perm [1,0,3,2]
#define DPP_XOR2 0x4E   // quad_perm [2,3,0,1]
#define DPP_ROR4 0x124  // row_ror:4
#define DPP_ROR8 0x128  // row_ror:8

__device__ __forceinline__ float other_half(float v) {
  unsigned b = __float_as_uint(v);
  auto sw = __builtin_amdgcn_permlane32_swap(b, b, false, false);
  return __uint_as_float(b ^ sw[0] ^ sw[1]);   // value from lane^32, any order
}

__global__ __launch_bounds__(64, 2) void tnn_scan(
    const float* __restrict__ in,    // (4096, 512, 7)
    const float* __restrict__ caps,  // (1, 4)
    const float* __restrict__ Wg,    // (11, 15)
    const float* __restrict__ bg,    // (15)
    const float* __restrict__ Wp1,   // (11, 16)
    const float* __restrict__ bp1,   // (16)
    const float* __restrict__ Wp2,   // (16, 4)
    const float* __restrict__ bp2,   // (4)
    float* __restrict__ out)         // (4096, 512, 4)
{
  __shared__ float xb[2][2][449];    // 2 buf x 2 chains x 448 (+1 pad)

  const int lane  = threadIdx.x;
  const int chain = (lane >> 4) & 1;
  const int u     = lane & 15;
  const bool hB   = (lane >= 32);    // false: conduct half, true: h half
  const int ur    = u & 3;

  const int elem = (int)blockIdx.x * 2 + chain;

  // conduct pair table: 0:(0,1) 1:(0,2) 2:(0,3) 3:(0,4) 4:(0,5) 5:(1,2)
  // 6:(1,3) 7:(1,4) 8:(1,5) 9:(2,3) 10:(2,4) 11:(2,5) 12:(3,4) 13:(3,5)
  // 14:(4,5)=dead (no output row)
  const int ug = (u < 15) ? u : 14;
  const unsigned long long IPACK = 0x4433222111100000ULL;
  const unsigned long long JPACK = 0x5554543543254321ULL;
  const int pi = (int)((IPACK >> (4 * ug)) & 15);
  const int pj = (int)((JPACK >> (4 * ug)) & 15);

  float wv0, wv1, wv2, wv3, wv4, wv5, wv6, wv7, wv8, wv9, wv10, bias;
  float mexp, cA, cB;
  float w20, w21, w22, w23;
  float is0, is1, is2, is3, tj1, tj2, tj3, tj4, tj5;
  if (!hB) {  // conduct column ug -> sigmoid
    wv0 = Wg[0*15+ug]; wv1 = Wg[1*15+ug]; wv2 = Wg[2*15+ug];
    wv3 = Wg[3*15+ug]; wv4 = Wg[4*15+ug]; wv5 = Wg[5*15+ug];
    wv6 = Wg[6*15+ug]; wv7 = Wg[7*15+ug]; wv8 = Wg[8*15+ug];
    wv9 = Wg[9*15+ug]; wv10 = Wg[10*15+ug]; bias = bg[ug];
    mexp = -1.0f; cA = 1.0f; cB = 0.0f;          // sigmoid(z)
    w20 = w21 = w22 = w23 = 0.0f;
    is0 = (pi == 0) ? 1.f : 0.f; is1 = (pi == 1) ? 1.f : 0.f;
    is2 = (pi == 2) ? 1.f : 0.f; is3 = (pi == 3) ? 1.f : 0.f;
    tj1 = (pj == 1) ? 1.f : 0.f; tj2 = (pj == 2) ? 1.f : 0.f;
    tj3 = (pj == 3) ? 1.f : 0.f; tj4 = (pj == 4) ? 1.f : 0.f;
    tj5 = (pj == 5) ? 1.f : 0.f;
  } else {    // h column u -> tanh
    wv0 = Wp1[0*16+u]; wv1 = Wp1[1*16+u]; wv2 = Wp1[2*16+u];
    wv3 = Wp1[3*16+u]; wv4 = Wp1[4*16+u]; wv5 = Wp1[5*16+u];
    wv6 = Wp1[6*16+u]; wv7 = Wp1[7*16+u]; wv8 = Wp1[8*16+u];
    wv9 = Wp1[9*16+u]; wv10 = Wp1[10*16+u]; bias = bp1[u];
    mexp = 2.0f; cA = -2.0f; cB = 1.0f;          // tanh(z) = 1 - 2/(1+e^2z)
    w20 = Wp2[u*4+0]; w21 = Wp2[u*4+1]; w22 = Wp2[u*4+2]; w23 = Wp2[u*4+3];
    is0 = is1 = is2 = is3 = 0.f;
    tj1 = tj2 = tj3 = tj4 = tj5 = 0.f;
  }

  // half-combine constants: conduct-own = t_r (B=0, identity mask);
  // h-own = |p_r + b2r| (B=b2r, abs mask)
  const float B0 = hB ? bp2[0] : 0.0f;
  const float B1 = hB ? bp2[1] : 0.0f;
  const float B2 = hB ? bp2[2] : 0.0f;
  const float B3 = hB ? bp2[3] : 0.0f;
  const unsigned MABS = hB ? 0x7FFFFFFFu : 0xFFFFFFFFu;

  const float LN10 = 2.302585092994046f;
  const float kc0 = 0.5f * __expf(caps[0] * LN10);
  const float kc1 = 0.5f * __expf(caps[1] * LN10);
  const float kc2 = 0.5f * __expf(caps[2] * LN10);
  const float kc3 = 0.5f * __expf(caps[3] * LN10);

  float s0 = 0.f, s1 = 0.f, s2 = 0.f, s3 = 0.f;

  const float* inblk = in + (size_t)((int)blockIdx.x * 2) * 3584;  // 512*7
  float* op = out + (size_t)elem * 2048 + ur;  // all lanes store (8 dup/addr)

  float stg[2][7];
  auto LOADC = [&](int cc) {
    #pragma unroll
    for (int e = 0; e < 2; ++e)
      #pragma unroll
      for (int k = 0; k < 7; ++k)
        stg[e][k] = inblk[(size_t)e * 3584 + cc * 448 + k * 64 + lane];
  };
  auto WRITEC = [&](int bb) {
    #pragma unroll
    for (int e = 0; e < 2; ++e)
      #pragma unroll
      for (int k = 0; k < 7; ++k)
        xb[bb][e][k * 64 + lane] = stg[e][k];
  };

  LOADC(0);
  WRITEC(0);

  #pragma unroll 1
  for (int c = 0; c < 8; ++c) {
    if (c < 7) LOADC(c + 1);          // global prefetch, 64 steps of slack
    const int cb = c & 1;

    #pragma unroll 4
    for (int tin = 0; tin < 64; ++tin) {
      const int t = c * 64 + tin;
      const float* xr = &xb[cb][chain][tin * 7];
      const float x0 = xr[0], x1 = xr[1], x2 = xr[2], x3 = xr[3],
                  x4 = xr[4], x5 = xr[5], x6 = xr[6];

      // one 11-FMA column per lane (all_in = [x0..x4, s0..s3, x5, x6])
      float z = fmaf(x0, wv0, fmaf(x1, wv1, fmaf(x2, wv2, fmaf(x3, wv3,
                fmaf(x4, wv4, fmaf(x5, wv9, fmaf(x6, wv10, bias)))))));
      z = fmaf(s0, wv5, fmaf(s1, wv6, fmaf(s2, wv7, fmaf(s3, wv8, z))));

      // unified nonlinearity: sigmoid / tanh, divergence-free
      const float e1 = __expf(z * mexp);
      const float rr = __fdividef(1.0f, 1.0f + e1);
      const float val = fmaf(rr, cA, cB);

      // conduct scatter prep (zero-masked on h half)
      const float txx = fmaf(tj4, x5, tj5 * x6);
      const float sjp = fmaf(tj1, s1, fmaf(tj2, s2, tj3 * s3));
      const float Si  = fmaf(is0, s0, fmaf(is1, s1, fmaf(is2, s2, is3 * s3)));
      const float gS  = val * Si;
      const float Tj  = sjp + txx;
      const float ci  = fmaf(val, Tj, -gS);    // g*(T_pj - s_pi)
      const float cj  = fmaf(-val, sjp, gS);   // g*(s_pi - s_pj)

      // per-row contribution: conduct lanes -> t_r, h lanes -> p_r
      float v0 = fmaf(val, w20, is0 * ci);
      float v1 = fmaf(val, w21, fmaf(is1, ci, tj1 * cj));
      float v2 = fmaf(val, w22, fmaf(is2, ci, tj2 * cj));
      float v3 = fmaf(val, w23, fmaf(is3, ci, tj3 * cj));

      // 16-lane DPP tree within each quarter-wave row
      v0 = dppadd<DPP_XOR1>(v0); v1 = dppadd<DPP_XOR1>(v1);
      v2 = dppadd<DPP_XOR1>(v2); v3 = dppadd<DPP_XOR1>(v3);
      v0 = dppadd<DPP_XOR2>(v0); v1 = dppadd<DPP_XOR2>(v1);
      v2 = dppadd<DPP_XOR2>(v2); v3 = dppadd<DPP_XOR2>(v3);
      v0 = dppadd<DPP_ROR4>(v0); v1 = dppadd<DPP_ROR4>(v1);
      v2 = dppadd<DPP_ROR4>(v2); v3 = dppadd<DPP_ROR4>(v3);
      v0 = dppadd<DPP_ROR8>(v0); v1 = dppadd<DPP_ROR8>(v1);
      v2 = dppadd<DPP_ROR8>(v2); v3 = dppadd<DPP_ROR8>(v3);
      // conduct rows hold t_r; h rows hold p_r

      // own value: conduct -> t_r ; h -> |p_r + b2r|
      const float o0 = __uint_as_float(__float_as_uint(v0 + B0) & MABS);
      const float o1 = __uint_as_float(__float_as_uint(v1 + B1) & MABS);
      const float o2 = __uint_as_float(__float_as_uint(v2 + B2) & MABS);
      const float o3 = __uint_as_float(__float_as_uint(v3 + B3) & MABS);

      // u_r = own + other-half value (t + |p+b| on both halves, bit-identical)
      const float u0 = o0 + other_half(o0);
      const float u1 = o1 + other_half(o1);
      const float u2 = o2 + other_half(o2);
      const float u3 = o3 + other_half(o3);

      // emit prev state (outs[t] = state before consuming x_t)
      const float sa = (ur & 1) ? s1 : s0;
      const float sb = (ur & 1) ? s3 : s2;
      op[t * 4] = (ur & 2) ? sb : sa;

      // Euler update + clip
      s0 = __builtin_amdgcn_fmed3f(fmaf(kc0, u0, s0), -1.0f, 5.0f);
      s1 = __builtin_amdgcn_fmed3f(fmaf(kc1, u1, s1), -1.0f, 5.0f);
      s2 = __builtin_amdgcn_fmed3f(fmaf(kc2, u2, s2), -1.0f, 5.0f);
      s3 = __builtin_amdgcn_fmed3f(fmaf(kc3, u3, s3), -1.0f, 5.0f);
    }

    if (c < 7) WRITEC((c + 1) & 1);   // commit prefetched chunk
  }
}

extern "C" void kernel_launch(void* const* d_in, const int* in_sizes, int n_in,
                              void* d_out, int out_size, void* d_ws, size_t ws_size,
                              hipStream_t stream) {
  const float* in   = (const float*)d_in[0];
  const float* caps = (const float*)d_in[1];
  const float* Wg   = (const float*)d_in[2];
  const float* bg   = (const float*)d_in[3];
  const float* Wp1  = (const float*)d_in[4];
  const float* bp1  = (const float*)d_in[5];
  const float* Wp2  = (const float*)d_in[6];
  const float* bp2  = (const float*)d_in[7];
  float* out = (float*)d_out;

  hipLaunchKernelGGL(tnn_scan, dim3(2048), dim3(64), 0, stream,
                     in, caps, Wg, bg, Wp1, bp1, Wp2, bp2, out);
}

// Round 8
// 233.893 us; speedup vs baseline: 1.2968x; 1.2968x over previous
//
#include <hip/hip_runtime.h>

// TNNCell scan: B=4096 chains, T=512 steps, 16 lanes/chain, 4 chains/wave.
// grid = 1024 blocks x 64 threads (1 wave/block) -> 1024 waves = 1 wave/SIMD.
//
// R7 = R2 layout (work-optimal: every lane does one conduct column AND one
// tanh column; 4 chains/wave share every instruction) + instruction-count
// cuts, targeting the ~2.5x gap between emitted stream and ideal:
//  - DPP tree via inline-asm v_add_f32 dpp (1 instr/stage, 32/step; the
//    update_dpp builtin can emit mov0+mov_dpp+add = 3/stage)
//  - bp2 bias folded into lane-15 p-contribution; |p| via abs src modifier
//  - weights prescaled by -log2e (sigmoid) / +2log2e (tanh): nonlinearity
//    = rcp(1+exp2(z)) with native v_exp_f32/v_rcp_f32, no muls, no divide glue

__device__ __forceinline__ float dpp_xor1(float v) {
  float r;
  asm("v_add_f32 %0, %1, %2 quad_perm:[1,0,3,2] row_mask:0xf bank_mask:0xf"
      : "=v"(r) : "v"(v), "v"(v));
  return r;
}
__device__ __forceinline__ float dpp_xor2(float v) {
  float r;
  asm("v_add_f32 %0, %1, %2 quad_perm:[2,3,0,1] row_mask:0xf bank_mask:0xf"
      : "=v"(r) : "v"(v), "v"(v));
  return r;
}
__device__ __forceinline__ float dpp_ror4(float v) {
  float r;
  asm("v_add_f32 %0, %1, %2 row_ror:4 row_mask:0xf bank_mask:0xf"
      : "=v"(r) : "v"(v), "v"(v));
  return r;
}
__device__ __forceinline__ float dpp_ror8(float v) {
  float r;
  asm("v_add_f32 %0, %1, %2 row_ror:8 row_mask:0xf bank_mask:0xf"
      : "=v"(r) : "v"(v), "v"(v));
  return r;
}

__global__ __launch_bounds__(64, 1) void tnn_scan(
    const float* __restrict__ in,    // (4096, 512, 7)
    const float* __restrict__ caps,  // (1, 4)
    const float* __restrict__ Wg,    // (11, 15)
    const float* __restrict__ bg,    // (15)
    const float* __restrict__ Wp1,   // (11, 16)
    const float* __restrict__ bp1,   // (16)
    const float* __restrict__ Wp2,   // (16, 4)
    const float* __restrict__ bp2,   // (4)
    float* __restrict__ out)         // (4096, 512, 4)
{
  __shared__ float xb[2][4][449];

  const int lane = threadIdx.x;
  const int grp  = lane >> 4;
  const int u    = lane & 15;
  const int ur   = u & 3;

  const int elem = (int)blockIdx.x * 4 + grp;

  // prescale: sigmoid needs exp(-z)=exp2(-L*z); tanh needs exp(2z)=exp2(2L*z)
  const float L  = 1.4426950408889634f;   // log2(e)
  const float SG = -L, TH = 2.0f * L;

  const int ug = (u < 15) ? u : 14;       // conduct col (14 dead; lane15 dups)
  const float wg0 = Wg[0*15+ug]*SG, wg1 = Wg[1*15+ug]*SG, wg2 = Wg[2*15+ug]*SG,
              wg3 = Wg[3*15+ug]*SG, wg4 = Wg[4*15+ug]*SG, wg5 = Wg[5*15+ug]*SG,
              wg6 = Wg[6*15+ug]*SG, wg7 = Wg[7*15+ug]*SG, wg8 = Wg[8*15+ug]*SG,
              wg9 = Wg[9*15+ug]*SG, wg10 = Wg[10*15+ug]*SG;
  const float bgc = bg[ug]*SG;
  const float wp0 = Wp1[0*16+u]*TH, wp1 = Wp1[1*16+u]*TH, wp2 = Wp1[2*16+u]*TH,
              wp3 = Wp1[3*16+u]*TH, wp4 = Wp1[4*16+u]*TH, wp5 = Wp1[5*16+u]*TH,
              wp6 = Wp1[6*16+u]*TH, wp7 = Wp1[7*16+u]*TH, wp8 = Wp1[8*16+u]*TH,
              wp9 = Wp1[9*16+u]*TH, wp10 = Wp1[10*16+u]*TH;
  const float bhc = bp1[u]*TH;
  const float w20 = Wp2[u*4+0], w21 = Wp2[u*4+1], w22 = Wp2[u*4+2], w23 = Wp2[u*4+3];

  // bp2 folded into lane-15's p contribution (tree-summed once per chain)
  const float bb0 = (u == 15) ? bp2[0] : 0.f;
  const float bb1 = (u == 15) ? bp2[1] : 0.f;
  const float bb2 = (u == 15) ? bp2[2] : 0.f;
  const float bb3 = (u == 15) ? bp2[3] : 0.f;

  const float LN10 = 2.302585092994046f;
  const float kc0 = 0.5f * __expf(caps[0] * LN10);
  const float kc1 = 0.5f * __expf(caps[1] * LN10);
  const float kc2 = 0.5f * __expf(caps[2] * LN10);
  const float kc3 = 0.5f * __expf(caps[3] * LN10);

  // conduct pair (pi,pj) for conduct index ug
  const unsigned long long IPACK = 0x4433222111100000ULL;
  const unsigned long long JPACK = 0x5554543543254321ULL;
  const int pi = (int)((IPACK >> (4 * ug)) & 15);
  const int pj = (int)((JPACK >> (4 * ug)) & 15);
  const float is0 = (pi == 0) ? 1.f : 0.f, is1 = (pi == 1) ? 1.f : 0.f,
              is2 = (pi == 2) ? 1.f : 0.f, is3 = (pi == 3) ? 1.f : 0.f;
  const float tj1 = (pj == 1) ? 1.f : 0.f, tj2 = (pj == 2) ? 1.f : 0.f,
              tj3 = (pj == 3) ? 1.f : 0.f, tj4 = (pj == 4) ? 1.f : 0.f,
              tj5 = (pj == 5) ? 1.f : 0.f;
  // lane u=15: dup col14 = pair(4,5): is*=0, tj1..3=0 -> all contribs dead

  float s0 = 0.f, s1 = 0.f, s2 = 0.f, s3 = 0.f;

  const float* inblk = in + (size_t)((int)blockIdx.x * 4) * 3584;
  float* op = out + (size_t)elem * 2048 + ur;

  float stg[4][7];
  auto LOADC = [&](int cc) {
    #pragma unroll
    for (int e = 0; e < 4; ++e)
      #pragma unroll
      for (int k = 0; k < 7; ++k)
        stg[e][k] = inblk[(size_t)e * 3584 + cc * 448 + k * 64 + lane];
  };
  auto WRITEC = [&](int bb) {
    #pragma unroll
    for (int e = 0; e < 4; ++e)
      #pragma unroll
      for (int k = 0; k < 7; ++k)
        xb[bb][e][k * 64 + lane] = stg[e][k];
  };

  LOADC(0);
  WRITEC(0);

  #pragma unroll 1
  for (int c = 0; c < 8; ++c) {
    if (c < 7) LOADC(c + 1);          // global prefetch, 64 steps of slack
    const int cb = c & 1;

    #pragma unroll 4
    for (int tin = 0; tin < 64; ++tin) {
      const int t = c * 64 + tin;
      const float* xr = &xb[cb][grp][tin * 7];
      const float x0 = xr[0], x1 = xr[1], x2 = xr[2], x3 = xr[3],
                  x4 = xr[4], x5 = xr[5], x6 = xr[6];

      // layer-1 dots (prescaled weights), split for latency
      float zgA = fmaf(x0, wg0, fmaf(x2, wg2, fmaf(x4, wg4,
                  fmaf(s1, wg6, fmaf(s3, wg8, fmaf(x6, wg10, bgc))))));
      float zgB = fmaf(x1, wg1, fmaf(x3, wg3, fmaf(s0, wg5,
                  fmaf(s2, wg7, x5 * wg9))));
      float zhA = fmaf(x0, wp0, fmaf(x2, wp2, fmaf(x4, wp4,
                  fmaf(s1, wp6, fmaf(s3, wp8, fmaf(x6, wp10, bhc))))));
      float zhB = fmaf(x1, wp1, fmaf(x3, wp3, fmaf(s0, wp5,
                  fmaf(s2, wp7, x5 * wp9))));
      const float zg = zgA + zgB;          // = -log2e * (all_in.Wg + bg)
      const float zh = zhA + zhB;          // =  2log2e * (all_in.Wp1 + bp1)

      // g = 1/(1+exp(-z)) ; h = 1 - 2/(1+exp(2z)) — native exp2/rcp
      const float g = __builtin_amdgcn_rcpf(1.0f + __builtin_amdgcn_exp2f(zg));
      const float rh = __builtin_amdgcn_rcpf(1.0f + __builtin_amdgcn_exp2f(zh));
      const float h = fmaf(rh, -2.0f, 1.0f);

      // p contributions with bias folded into lane 15
      float p0 = fmaf(h, w20, bb0), p1 = fmaf(h, w21, bb1),
            p2 = fmaf(h, w22, bb2), p3 = fmaf(h, w23, bb3);

      // temp-diff scatter: pair (pi,pj); d = s_pi - s_pj
      const float txx = fmaf(tj4, x5, tj5 * x6);
      const float sjp = fmaf(tj1, s1, fmaf(tj2, s2, tj3 * s3));
      const float Si  = fmaf(is0, s0, fmaf(is1, s1, fmaf(is2, s2, is3 * s3)));
      const float d   = Si - sjp;
      const float gd  = g * d;
      const float ci  = fmaf(g, txx, -gd);   // g*(T_pj - s_pi)
      const float cj  = gd;                  // g*(s_pi - s_pj)
      float t0 = is0 * ci;
      float t1 = fmaf(is1, ci, tj1 * cj);
      float t2 = fmaf(is2, ci, tj2 * cj);
      float t3 = fmaf(is3, ci, tj3 * cj);

      // 16-lane all-reduce of 8 vars: 32 x v_add_f32_dpp exactly
      p0 = dpp_xor1(p0); p1 = dpp_xor1(p1); p2 = dpp_xor1(p2); p3 = dpp_xor1(p3);
      t0 = dpp_xor1(t0); t1 = dpp_xor1(t1); t2 = dpp_xor1(t2); t3 = dpp_xor1(t3);
      p0 = dpp_xor2(p0); p1 = dpp_xor2(p1); p2 = dpp_xor2(p2); p3 = dpp_xor2(p3);
      t0 = dpp_xor2(t0); t1 = dpp_xor2(t1); t2 = dpp_xor2(t2); t3 = dpp_xor2(t3);
      p0 = dpp_ror4(p0); p1 = dpp_ror4(p1); p2 = dpp_ror4(p2); p3 = dpp_ror4(p3);
      t0 = dpp_ror4(t0); t1 = dpp_ror4(t1); t2 = dpp_ror4(t2); t3 = dpp_ror4(t3);
      p0 = dpp_ror8(p0); p1 = dpp_ror8(p1); p2 = dpp_ror8(p2); p3 = dpp_ror8(p3);
      t0 = dpp_ror8(t0); t1 = dpp_ror8(t1); t2 = dpp_ror8(t2); t3 = dpp_ror8(t3);

      // emit prev state (outs[t] = state before consuming x_t)
      const float sout = (ur == 0) ? s0 : (ur == 1) ? s1 : (ur == 2) ? s2 : s3;
      if (u < 4) op[t * 4] = sout;

      // u_r = t_r + |p_r| (abs as src modifier), Euler + clip
      const float u0 = t0 + fabsf(p0);
      const float u1 = t1 + fabsf(p1);
      const float u2 = t2 + fabsf(p2);
      const float u3 = t3 + fabsf(p3);
      s0 = __builtin_amdgcn_fmed3f(fmaf(kc0, u0, s0), -1.0f, 5.0f);
      s1 = __builtin_amdgcn_fmed3f(fmaf(kc1, u1, s1), -1.0f, 5.0f);
      s2 = __builtin_amdgcn_fmed3f(fmaf(kc2, u2, s2), -1.0f, 5.0f);
      s3 = __builtin_amdgcn_fmed3f(fmaf(kc3, u3, s3), -1.0f, 5.0f);
    }

    if (c < 7) WRITEC((c + 1) & 1);   // commit prefetched chunk
  }
}

extern "C" void kernel_launch(void* const* d_in, const int* in_sizes, int n_in,
                              void* d_out, int out_size, void* d_ws, size_t ws_size,
                              hipStream_t stream) {
  const float* in   = (const float*)d_in[0];
  const float* caps = (const float*)d_in[1];
  const float* Wg   = (const float*)d_in[2];
  const float* bg   = (const float*)d_in[3];
  const float* Wp1  = (const float*)d_in[4];
  const float* bp1  = (const float*)d_in[5];
  const float* Wp2  = (const float*)d_in[6];
  const float* bp2  = (const float*)d_in[7];
  float* out = (float*)d_out;

  hipLaunchKernelGGL(tnn_scan, dim3(1024), dim3(64), 0, stream,
                     in, caps, Wg, bg, Wp1, bp1, Wp2, bp2, out);
}